// Round 1
// baseline (1435.293 us; speedup 1.0000x reference)
//
#include <hip/hip_runtime.h>
#include <stdint.h>

#define N_TOK 32768
#define D_IN  512
#define H_DIM 2048
#define O_DIM 512
#define N_EXP 8
#define BM    64
#define BH    128

typedef __bf16 bf16x8 __attribute__((ext_vector_type(8)));
typedef float  f32x4  __attribute__((ext_vector_type(4)));

struct alignas(8) us4 { unsigned short x, y, z, w; };

__device__ __forceinline__ unsigned short f2bf(float f) {
  union { float f; unsigned u; } v; v.f = f;
  unsigned r = v.u + 0x7FFFu + ((v.u >> 16) & 1u);  // round-to-nearest-even
  return (unsigned short)(r >> 16);
}

// ---------------- init: zero counts ----------------
__global__ void k_init(int* counts) {
  if (threadIdx.x < N_EXP) counts[threadIdx.x] = 0;
}

// ---------------- weight convert + transpose to bf16 ----------------
// W (E, R, C) fp32 row-major  ->  WT (E, C, R) bf16
__global__ void k_transpose(const float* __restrict__ W, unsigned short* __restrict__ WT,
                            int R, int C) {
  __shared__ unsigned short tile[64][72];
  int e = blockIdx.y;
  const float* src = W + (size_t)e * R * C;
  unsigned short* dst = WT + (size_t)e * R * C;
  int tilesC = C >> 6;
  int tc = (blockIdx.x % tilesC) << 6;
  int tr = (blockIdx.x / tilesC) << 6;
  int tid = threadIdx.x;
  int rq = tid >> 4;      // 0..15
  int cq = tid & 15;      // 0..15
#pragma unroll
  for (int q = 0; q < 4; ++q) {
    int r = q * 16 + rq;
    float4 v = *(const float4*)(src + (size_t)(tr + r) * C + tc + cq * 4);
    tile[r][cq * 4 + 0] = f2bf(v.x);
    tile[r][cq * 4 + 1] = f2bf(v.y);
    tile[r][cq * 4 + 2] = f2bf(v.z);
    tile[r][cq * 4 + 3] = f2bf(v.w);
  }
  __syncthreads();
#pragma unroll
  for (int q = 0; q < 4; ++q) {
    int cc = q * 16 + rq;   // output row (= original col)
    int rr = cq * 4;        // output cols (= original rows)
    us4 o;
    o.x = tile[rr + 0][cc]; o.y = tile[rr + 1][cc];
    o.z = tile[rr + 2][cc]; o.w = tile[rr + 3][cc];
    *(us4*)(dst + (size_t)(tc + cc) * R + tr + rr) = o;
  }
}

// ---------------- router: fp32, wave per token ----------------
__global__ void k_router(const float* __restrict__ x, const float* __restrict__ Wr,
                         const float* __restrict__ br, int* __restrict__ expert_id,
                         int* __restrict__ counts) {
  int token = blockIdx.x * 4 + (threadIdx.x >> 6);
  int lane  = threadIdx.x & 63;
  const float* xr = x + (size_t)token * D_IN;
  float acc[N_EXP];
#pragma unroll
  for (int e = 0; e < N_EXP; ++e) acc[e] = 0.f;
#pragma unroll
  for (int j = 0; j < 2; ++j) {
    int i0 = lane * 8 + j * 4;
    float4 xv = *(const float4*)(xr + i0);
    float xs[4] = {xv.x, xv.y, xv.z, xv.w};
#pragma unroll
    for (int u = 0; u < 4; ++u) {
      const float4* wr = (const float4*)(Wr + (size_t)(i0 + u) * N_EXP);
      float4 w0 = wr[0], w1 = wr[1];
      acc[0] += xs[u] * w0.x; acc[1] += xs[u] * w0.y;
      acc[2] += xs[u] * w0.z; acc[3] += xs[u] * w0.w;
      acc[4] += xs[u] * w1.x; acc[5] += xs[u] * w1.y;
      acc[6] += xs[u] * w1.z; acc[7] += xs[u] * w1.w;
    }
  }
#pragma unroll
  for (int off = 32; off > 0; off >>= 1) {
#pragma unroll
    for (int e = 0; e < N_EXP; ++e) acc[e] += __shfl_xor(acc[e], off, 64);
  }
  if (lane == 0) {
    float best = acc[0] + br[0]; int bi = 0;
#pragma unroll
    for (int e = 1; e < N_EXP; ++e) {
      float v = acc[e] + br[e];
      if (v > best) { best = v; bi = e; }   // strict > : first max wins (matches top_k)
    }
    expert_id[token] = bi;
    atomicAdd(&counts[bi], 1);
  }
}

// ---------------- scan: offsets + cursors ----------------
__global__ void k_scan(const int* __restrict__ counts, int* __restrict__ offsets,
                       int* __restrict__ cursor) {
  if (threadIdx.x == 0) {
    int s = 0;
    for (int e = 0; e < N_EXP; ++e) { offsets[e] = s; cursor[e] = s; s += counts[e]; }
  }
}

// ---------------- scatter tokens into per-expert lists ----------------
__global__ void k_scatter(const int* __restrict__ expert_id, int* __restrict__ cursor,
                          int* __restrict__ idx_list) {
  int i = blockIdx.x * 256 + threadIdx.x;
  int e = expert_id[i];
  int pos = atomicAdd(&cursor[e], 1);
  idx_list[pos] = i;
}

// ---------------- fused MoE MLP ----------------
// grid = 8 * (N_TOK/BM); expert = bid & 7 (XCD affinity), tile = bid >> 3
__launch_bounds__(512, 4)
__global__ void k_moe(const float* __restrict__ x,
                      const unsigned short* __restrict__ W1T,   // (E, H, D) bf16
                      const unsigned short* __restrict__ W2T,   // (E, O, H) bf16
                      const float* __restrict__ b1, const float* __restrict__ b2,
                      const int* __restrict__ counts, const int* __restrict__ offsets,
                      const int* __restrict__ idx_list,
                      float* __restrict__ out) {
  int e = blockIdx.x & 7;
  int t = blockIdx.x >> 3;
  int cnt = counts[e];
  if (t * BM >= cnt) return;
  int base   = offsets[e] + t * BM;
  int mvalid = min(BM, cnt - t * BM);

  __shared__ __align__(16) unsigned short Xs[BM * D_IN];  // 64 KB, XOR-swizzled
  __shared__ __align__(16) unsigned short Hs[BM * BH];    // 16 KB, XOR-swizzled

  int tid  = threadIdx.x;
  int wave = tid >> 6;
  int lane = tid & 63;
  int l15  = lane & 15;
  int l4   = lane >> 4;

  // ---- stage X rows (gather, fp32 -> bf16, swizzled) ----
#pragma unroll
  for (int rr = 0; rr < 8; ++rr) {
    int row = wave * 8 + rr;
    int tok = idx_list[base + (row < mvalid ? row : 0)];
    const float4* src = (const float4*)(x + (size_t)tok * D_IN);
#pragma unroll
    for (int p = 0; p < 2; ++p) {
      float4 v = src[p * 64 + lane];
      us4 b;
      b.x = f2bf(v.x); b.y = f2bf(v.y); b.z = f2bf(v.z); b.w = f2bf(v.w);
      int baddr = row * (D_IN * 2) + (p * 512 + lane * 8);
      baddr ^= ((row & 7) << 4);
      *(us4*)((char*)Xs + baddr) = b;
    }
  }
  __syncthreads();

  f32x4 acc2[4][4];
#pragma unroll
  for (int a = 0; a < 4; ++a)
#pragma unroll
    for (int b = 0; b < 4; ++b) acc2[a][b] = (f32x4){0.f, 0.f, 0.f, 0.f};

  const unsigned short* w1base = W1T + ((size_t)e * H_DIM + l15) * D_IN + l4 * 8;
  const unsigned short* w2base = W2T + ((size_t)e * O_DIM + wave * 64 + l15) * H_DIM + l4 * 8;

  for (int ch = 0; ch < H_DIM / BH; ++ch) {
    // ---- GEMM1: this wave computes H[0:64, ch*BH + wave*16 .. +16) ----
    int hcol0 = ch * BH + wave * 16;
    f32x4 acc1[4];
#pragma unroll
    for (int a = 0; a < 4; ++a) acc1[a] = (f32x4){0.f, 0.f, 0.f, 0.f};
    const unsigned short* w1p = w1base + (size_t)hcol0 * D_IN;
#pragma unroll
    for (int ks = 0; ks < D_IN / 32; ++ks) {
      bf16x8 bfrag = *(const bf16x8*)(w1p + ks * 32);
#pragma unroll
      for (int rf = 0; rf < 4; ++rf) {
        int row = rf * 16 + l15;
        int baddr = row * (D_IN * 2) + (ks * 32 + l4 * 8) * 2;
        baddr ^= ((row & 7) << 4);
        bf16x8 afrag = *(const bf16x8*)((const char*)Xs + baddr);
        acc1[rf] = __builtin_amdgcn_mfma_f32_16x16x32_bf16(afrag, bfrag, acc1[rf], 0, 0, 0);
      }
    }
    // bias + relu + bf16 -> Hs (swizzled)
    float b1v = b1[(size_t)e * H_DIM + hcol0 + l15];
#pragma unroll
    for (int rf = 0; rf < 4; ++rf) {
#pragma unroll
      for (int j = 0; j < 4; ++j) {
        float v = acc1[rf][j] + b1v;
        v = fmaxf(v, 0.f);
        int row = rf * 16 + l4 * 4 + j;
        int col = wave * 16 + l15;
        int baddr = row * (BH * 2) + col * 2;
        baddr ^= ((row & 7) << 4);
        *(unsigned short*)((char*)Hs + baddr) = f2bf(v);
      }
    }
    __syncthreads();

    // ---- GEMM2: wave computes O[0:64, wave*64 .. +64) += Hs @ W2T-slice ----
    const unsigned short* w2p = w2base + ch * BH;
#pragma unroll
    for (int ks2 = 0; ks2 < BH / 32; ++ks2) {
      bf16x8 af[4];
#pragma unroll
      for (int rf = 0; rf < 4; ++rf) {
        int row = rf * 16 + l15;
        int baddr = row * (BH * 2) + (ks2 * 32 + l4 * 8) * 2;
        baddr ^= ((row & 7) << 4);
        af[rf] = *(const bf16x8*)((const char*)Hs + baddr);
      }
#pragma unroll
      for (int cf = 0; cf < 4; ++cf) {
        bf16x8 bfrag = *(const bf16x8*)(w2p + (size_t)cf * 16 * H_DIM + ks2 * 32);
#pragma unroll
        for (int rf = 0; rf < 4; ++rf)
          acc2[rf][cf] = __builtin_amdgcn_mfma_f32_16x16x32_bf16(af[rf], bfrag, acc2[rf][cf], 0, 0, 0);
      }
    }
    __syncthreads();
  }

  // ---- epilogue: bias + scatter store (fp32) ----
#pragma unroll
  for (int cf = 0; cf < 4; ++cf) {
    int col = wave * 64 + cf * 16 + l15;
    float b2v = b2[(size_t)e * O_DIM + col];
#pragma unroll
    for (int rf = 0; rf < 4; ++rf) {
#pragma unroll
      for (int j = 0; j < 4; ++j) {
        int row = rf * 16 + l4 * 4 + j;
        if (row < mvalid) {
          int tok = idx_list[base + row];
          out[(size_t)tok * O_DIM + col] = acc2[rf][cf][j] + b2v;
        }
      }
    }
  }
}

// ---------------- launch ----------------
extern "C" void kernel_launch(void* const* d_in, const int* in_sizes, int n_in,
                              void* d_out, int out_size, void* d_ws, size_t ws_size,
                              hipStream_t stream) {
  const float* x  = (const float*)d_in[0];
  const float* Wr = (const float*)d_in[1];
  const float* br = (const float*)d_in[2];
  const float* W1 = (const float*)d_in[3];
  const float* b1 = (const float*)d_in[4];
  const float* W2 = (const float*)d_in[5];
  const float* b2 = (const float*)d_in[6];
  float* out = (float*)d_out;

  char* ws = (char*)d_ws;
  int* counts    = (int*)(ws + 0);
  int* offsets   = (int*)(ws + 32);
  int* cursor    = (int*)(ws + 64);
  int* expert_id = (int*)(ws + 1024);
  int* idx_list  = (int*)(ws + 1024 + N_TOK * 4);
  unsigned short* W1T = (unsigned short*)(ws + 1024 + 2 * N_TOK * 4 + 512);          // 16 MB
  unsigned short* W2T = W1T + (size_t)N_EXP * H_DIM * D_IN;                           // 16 MB

  k_init<<<1, 64, 0, stream>>>(counts);
  k_transpose<<<dim3(256, N_EXP), 256, 0, stream>>>(W1, W1T, D_IN, H_DIM);
  k_transpose<<<dim3(256, N_EXP), 256, 0, stream>>>(W2, W2T, H_DIM, O_DIM);
  k_router<<<N_TOK / 4, 256, 0, stream>>>(x, Wr, br, expert_id, counts);
  k_scan<<<1, 64, 0, stream>>>(counts, offsets, cursor);
  k_scatter<<<N_TOK / 256, 256, 0, stream>>>(expert_id, cursor, idx_list);
  k_moe<<<N_EXP * (N_TOK / BM), 512, 0, stream>>>(x, W1T, W2T, b1, b2,
                                                  counts, offsets, idx_list, out);
}